// Round 7
// baseline (50.639 us; speedup 1.0000x reference)
//
#include <hip/hip_runtime.h>

#define NNODE  18
#define ADJ_B  1296                     // bytes per batch matrix
#define ADJ_F  324                      // floats per batch matrix
#define TILE   20                       // batches per buffer
#define BUF_B  (TILE * ADJ_B)           // 25,920 ; x2 = 51,840 B -> 3 blocks/CU
#define WSTRIPE (BUF_B / 4)             // 6,480 B staged per wave
#define SOPS   7                        // DMA ops per wave per stage: 6 full + 1 partial(21 lanes)
#define GRID   768                      // persistent: 3 blocks/CU

__device__ __forceinline__ void gload_lds16(const void* g, void* l) {
    __builtin_amdgcn_global_load_lds((const __attribute__((address_space(1))) void*)g,
                                     (__attribute__((address_space(3))) void*)l, 16, 0, 0);
}

// quad_perm broadcast of lane P within each 4-lane group (bit15=1 -> quad mode)
#define QB(v, P) __int_as_float(__builtin_amdgcn_ds_swizzle(__float_as_int(v), 0x8000 + 0x55 * (P)))
#define GATHER18(dst, src)                                                      \
    dst[0]=QB(src[0],0);  dst[1]=QB(src[0],1);  dst[2]=QB(src[0],2);  dst[3]=QB(src[0],3);   \
    dst[4]=QB(src[1],0);  dst[5]=QB(src[1],1);  dst[6]=QB(src[1],2);  dst[7]=QB(src[1],3);   \
    dst[8]=QB(src[2],0);  dst[9]=QB(src[2],1);  dst[10]=QB(src[2],2); dst[11]=QB(src[2],3);  \
    dst[12]=QB(src[3],0); dst[13]=QB(src[3],1); dst[14]=QB(src[3],2); dst[15]=QB(src[3],3);  \
    dst[16]=QB(src[4],0); dst[17]=QB(src[4],1);

__global__ __launch_bounds__(256, 3) void gcnn_fused(
    const float* __restrict__ nf, const float* __restrict__ adj,
    const float* __restrict__ proj_w, const float* __restrict__ proj_b,
    const float* __restrict__ w1, const float* __restrict__ b1,
    const float* __restrict__ w2, const float* __restrict__ b2,
    const float* __restrict__ w3, const float* __restrict__ b3,
    float* __restrict__ out, int B)
{
    extern __shared__ __align__(16) char smem[];   // 2 x BUF_B, LINEAR (DMA dest)
    const int tid  = threadIdx.x;
    const int wave = tid >> 6;
    const int lane = tid & 63;
    const int p    = lane & 3;                     // quad lane: owns rows r ≡ p (mod 4)
    const int q    = lane >> 2;                    // quad within wave; active if q < 5
    const int bt   = wave * 5 + q;                 // batch-in-tile (balanced across waves)
    const int NT   = (B + TILE - 1) / TILE;        // 6554
    const unsigned adjLim = (unsigned)B * ADJ_B - 16;

    char* bA = smem;
    char* bB = smem + BUF_B;

    // Fixed 7 DMA ops per wave, clamped global addresses -> exact vmcnt semantics.
    auto stage = [&](int t, char* buf) {
        const unsigned base = (unsigned)t * BUF_B + (unsigned)(wave * WSTRIPE) + lane * 16;
        char* ldst = buf + wave * WSTRIPE;
        #pragma unroll
        for (int c = 0; c < 6; ++c)
            gload_lds16((const char*)adj + min(base + c * 1024u, adjLim), ldst + c * 1024);
        if (lane < 21)                             // 336 B tail of the stripe; fixed predicate
            gload_lds16((const char*)adj + min(base + 6144u, adjLim), ldst + 6144);
    };

    int t = blockIdx.x;
    stage(t, bA);                                  // prologue: 7 ops in flight

    for (; t < NT; t += GRID) {
        const int b = t * TILE + bt;
        const bool act = (q < 5) && (b < B);

        // x loads BEFORE next stage: older in VM FIFO, retired by the vmcnt(7) below
        float x[NNODE];
        if (act) {
            const float2* __restrict__ xp = (const float2*)(nf + (size_t)b * NNODE);
            #pragma unroll
            for (int j = 0; j < 9; ++j) { float2 v = xp[j]; x[2*j] = v.x; x[2*j+1] = v.y; }
        }
        asm volatile("" ::: "memory");             // keep x-loads issued before the DMAs

        const int tn = t + GRID;
        if (tn < NT) {
            stage(tn, bB);                         // +7 ops (newest)
            asm volatile("s_waitcnt vmcnt(7)" ::: "memory");  // bufA + x resident; B in flight
        } else {
            asm volatile("s_waitcnt vmcnt(0)" ::: "memory");
        }
        __builtin_amdgcn_s_barrier();              // raw: does NOT drain vmcnt

        if (act) {
            // LDS -> registers: lane p reads rows 4u+p of its quad's batch
            float a[5][NNODE];
            const float* __restrict__ my = (const float*)bA + bt * ADJ_F;
            #pragma unroll
            for (int u = 0; u < 5; ++u) {
                int r  = 4 * u + p;
                int ro = r < NNODE ? r : NNODE - 1;   // lanes p>=2,u=4: clamped dummy
                const float2* __restrict__ rp = (const float2*)(my + ro * NNODE);
                #pragma unroll
                for (int j = 0; j < 9; ++j) { float2 v = rp[j]; a[u][2*j] = v.x; a[u][2*j+1] = v.y; }
            }

            const float pw = proj_w[0], pb = proj_b[0];

            // Layer 1: h = relu(pw*(A x)/deg + pb), deg = row-sum (A·1 = deg)
            float inv[5], h[5];
            #pragma unroll
            for (int u = 0; u < 5; ++u) {
                float d = 0.f, s = 0.f;
                #pragma unroll
                for (int m = 0; m < NNODE; ++m) { d += a[u][m]; s += a[u][m] * x[m]; }
                inv[u] = 1.0f / d;
                h[u]   = fmaxf(0.f, pw * s * inv[u] + pb);
            }

            float hf[NNODE];
            GATHER18(hf, h)

            // Layer 2 from register-resident A; NaN-scrub per reference
            float y[5];
            #pragma unroll
            for (int u = 0; u < 5; ++u) {
                float s = 0.f;
                #pragma unroll
                for (int m = 0; m < NNODE; ++m) s += a[u][m] * hf[m];
                float v = fmaxf(0.f, pw * s * inv[u] + pb);
                y[u] = (v != v) ? 0.f : v;
            }

            float yf[NNODE];
            GATHER18(yf, y)

            // MLP head (quad-redundant; weights lane-uniform -> scalar/broadcast loads)
            float z1[10];
            #pragma unroll
            for (int k = 0; k < 10; ++k) {
                float s = b1[k];
                #pragma unroll
                for (int j = 0; j < NNODE; ++j) s += w1[k*NNODE + j] * yf[j];
                z1[k] = fmaxf(0.f, s);
            }
            float z2[8];
            #pragma unroll
            for (int k = 0; k < 8; ++k) {
                float s = b2[k];
                #pragma unroll
                for (int j = 0; j < 10; ++j) s += w2[k*10 + j] * z1[j];
                z2[k] = fmaxf(0.f, s);
            }
            float o0 = b3[0], o1 = b3[1];
            #pragma unroll
            for (int j = 0; j < 8; ++j) { o0 += w3[j] * z2[j]; o1 += w3[8 + j] * z2[j]; }

            if (p == 0)
                *(float2*)(out + (size_t)b * 2) = make_float2(o0, o1);
        }

        asm volatile("" ::: "memory");             // no ds_read sinks past this point
        __builtin_amdgcn_s_barrier();              // all reads of bA done before overwrite
        char* tmp = bA; bA = bB; bB = tmp;
    }
}

extern "C" void kernel_launch(void* const* d_in, const int* in_sizes, int n_in,
                              void* d_out, int out_size, void* d_ws, size_t ws_size,
                              hipStream_t stream) {
    const float* nf  = (const float*)d_in[0];
    const float* adj = (const float*)d_in[1];
    const float* pw  = (const float*)d_in[2];
    const float* pb  = (const float*)d_in[3];
    const float* w1  = (const float*)d_in[4];
    const float* b1  = (const float*)d_in[5];
    const float* w2  = (const float*)d_in[6];
    const float* b2  = (const float*)d_in[7];
    const float* w3  = (const float*)d_in[8];
    const float* b3  = (const float*)d_in[9];
    float* out = (float*)d_out;

    const int B = in_sizes[0] / NNODE;              // 131072
    const size_t ldsBytes = 2 * BUF_B;              // 51,840 B -> 3 blocks/CU

    hipFuncSetAttribute(reinterpret_cast<const void*>(gcnn_fused),
                        hipFuncAttributeMaxDynamicSharedMemorySize, (int)ldsBytes);

    gcnn_fused<<<GRID, 256, ldsBytes, stream>>>(nf, adj, pw, pb, w1, b1, w2, b2, w3, b3, out, B);
}

// Round 8
// 48.932 us; speedup vs baseline: 1.0349x; 1.0349x over previous
//
#include <hip/hip_runtime.h>

#define NNODE  18
#define ADJ_B  1296                     // bytes per batch matrix
#define ADJ_F  324                      // floats per batch matrix
#define TILE   20                       // batches per buffer (block-wide)
#define BUF_B  (TILE * ADJ_B)           // 25,920 ; x2 = 51,840 -> 3 blocks/CU
#define WSTRIPE 6480                    // per-wave stripe = exactly 5 batches
#define BLK2   (2 * TILE)               // 40 batches per block (2-tile pipeline)

__device__ __forceinline__ void gload_lds16(const void* g, void* l) {
    __builtin_amdgcn_global_load_lds((const __attribute__((address_space(1))) void*)g,
                                     (__attribute__((address_space(3))) void*)l, 16, 0, 0);
}

// quad_perm broadcast of lane P within each 4-lane group (bit15=1 -> quad mode)
#define QB(v, P) __int_as_float(__builtin_amdgcn_ds_swizzle(__float_as_int(v), 0x8000 + 0x55 * (P)))
#define GATHER18(dst, src)                                                      \
    dst[0]=QB(src[0],0);  dst[1]=QB(src[0],1);  dst[2]=QB(src[0],2);  dst[3]=QB(src[0],3);   \
    dst[4]=QB(src[1],0);  dst[5]=QB(src[1],1);  dst[6]=QB(src[1],2);  dst[7]=QB(src[1],3);   \
    dst[8]=QB(src[2],0);  dst[9]=QB(src[2],1);  dst[10]=QB(src[2],2); dst[11]=QB(src[2],3);  \
    dst[12]=QB(src[3],0); dst[13]=QB(src[3],1); dst[14]=QB(src[3],2); dst[15]=QB(src[3],3);  \
    dst[16]=QB(src[4],0); dst[17]=QB(src[4],1);

__global__ __launch_bounds__(256, 3) void gcnn_fused(
    const float* __restrict__ nf, const float* __restrict__ adj,
    const float* __restrict__ proj_w, const float* __restrict__ proj_b,
    const float* __restrict__ w1, const float* __restrict__ b1,
    const float* __restrict__ w2, const float* __restrict__ b2,
    const float* __restrict__ w3, const float* __restrict__ b3,
    float* __restrict__ out, int B)
{
    extern __shared__ __align__(16) char smem[];   // 2 x BUF_B, LINEAR (DMA dest)
    const int tid  = threadIdx.x;                  // 4 waves; ZERO cross-wave deps, NO barriers
    const int wave = tid >> 6;
    const int lane = tid & 63;
    const int p    = lane & 3;                     // quad lane: owns rows r ≡ p (mod 4)
    const int q    = lane >> 2;                    // quad in wave; active if q < 5
    const bool qact = q < 5;
    const int bt   = wave * 5 + q;                 // batch-in-tile: wave computes what it stages
    const int b0   = blockIdx.x * BLK2;
    const unsigned adjLim = (unsigned)B * ADJ_B - 16;

    char* buf0 = smem;
    char* buf1 = smem + BUF_B;

    // Per-wave stripe stage: 7 DMA ops covering batches [tb + 5*wave, tb + 5*wave + 5)
    auto stage = [&](int tb, char* buf) {
        const unsigned gbase = (unsigned)(tb + wave * 5) * ADJ_B + lane * 16u;
        char* ldst = buf + wave * WSTRIPE;
        #pragma unroll
        for (int c = 0; c < 6; ++c)
            gload_lds16((const char*)adj + min(gbase + c * 1024u, adjLim), ldst + c * 1024);
        if (lane < 21)                             // stripe tail: 336 B, fixed predicate
            gload_lds16((const char*)adj + min(gbase + 6144u, adjLim), ldst + 6144);
    };

    auto loadx = [&](int b, float* x) {
        const float2* __restrict__ xp = (const float2*)(nf + (size_t)b * NNODE);
        #pragma unroll
        for (int j = 0; j < 9; ++j) { float2 v = xp[j]; x[2*j] = v.x; x[2*j+1] = v.y; }
    };

    auto compute = [&](int b, const float* x, const char* buf) {
        // LDS -> registers: lane p reads rows 4u+p of its quad's batch
        float a[5][NNODE];
        const float* __restrict__ my = (const float*)buf + bt * ADJ_F;
        #pragma unroll
        for (int u = 0; u < 5; ++u) {
            int r  = 4 * u + p;
            int ro = r < NNODE ? r : NNODE - 1;    // lanes p>=2,u=4: clamped dummy (unused)
            const float2* __restrict__ rp = (const float2*)(my + ro * NNODE);
            #pragma unroll
            for (int j = 0; j < 9; ++j) { float2 v = rp[j]; a[u][2*j] = v.x; a[u][2*j+1] = v.y; }
        }
        const float pw = proj_w[0], pb = proj_b[0];

        // Layer 1: h = relu(pw*(A x)/deg + pb), deg = row-sum (A·1 = deg, proj is 1x1)
        float inv[5], h[5];
        #pragma unroll
        for (int u = 0; u < 5; ++u) {
            float d = 0.f, s = 0.f;
            #pragma unroll
            for (int m = 0; m < NNODE; ++m) { d += a[u][m]; s += a[u][m] * x[m]; }
            inv[u] = 1.0f / d;
            h[u]   = fmaxf(0.f, pw * s * inv[u] + pb);
        }
        float hf[NNODE];
        GATHER18(hf, h)

        // Layer 2 from register-resident A; NaN-scrub per reference
        float y[5];
        #pragma unroll
        for (int u = 0; u < 5; ++u) {
            float s = 0.f;
            #pragma unroll
            for (int m = 0; m < NNODE; ++m) s += a[u][m] * hf[m];
            float v = fmaxf(0.f, pw * s * inv[u] + pb);
            y[u] = (v != v) ? 0.f : v;
        }
        float yf[NNODE];
        GATHER18(yf, y)

        // MLP head (quad-redundant; weights lane-uniform -> scalar/broadcast loads)
        float z1[10];
        #pragma unroll
        for (int k = 0; k < 10; ++k) {
            float s = b1[k];
            #pragma unroll
            for (int j = 0; j < NNODE; ++j) s += w1[k*NNODE + j] * yf[j];
            z1[k] = fmaxf(0.f, s);
        }
        float z2[8];
        #pragma unroll
        for (int k = 0; k < 8; ++k) {
            float s = b2[k];
            #pragma unroll
            for (int j = 0; j < 10; ++j) s += w2[k*10 + j] * z1[j];
            z2[k] = fmaxf(0.f, s);
        }
        float o0 = b3[0], o1 = b3[1];
        #pragma unroll
        for (int j = 0; j < 8; ++j) { o0 += w3[j] * z2[j]; o1 += w3[8 + j] * z2[j]; }

        if (p == 0)
            *(float2*)(out + (size_t)b * 2) = make_float2(o0, o1);
    };

    const int bA = b0 + bt;                // this wave's tile-0 batch
    const int bB = b0 + TILE + bt;         // this wave's tile-1 batch
    const bool actA = qact && bA < B;
    const bool actB = qact && bB < B;

    // ---- 2-tile per-wave pipeline, no barriers ----
    stage(b0, buf0);                                       // 7 ops
    float x0[NNODE];
    if (actA) loadx(bA, x0);                               // 9 loads (older than t1 stage)
    asm volatile("" ::: "memory");
    stage(b0 + TILE, buf1);                                // +7 ops (newest)
    asm volatile("s_waitcnt vmcnt(7)" ::: "memory");       // t0 + x0 resident; t1 in flight

    float x1[NNODE];
    if (actB) loadx(bB, x1);                               // latency hides under compute t0
    asm volatile("" ::: "memory");
    if (actA) compute(bA, x0, buf0);

    asm volatile("s_waitcnt vmcnt(0)" ::: "memory");       // t1 + x1 resident
    if (actB) compute(bB, x1, buf1);
}

extern "C" void kernel_launch(void* const* d_in, const int* in_sizes, int n_in,
                              void* d_out, int out_size, void* d_ws, size_t ws_size,
                              hipStream_t stream) {
    const float* nf  = (const float*)d_in[0];
    const float* adj = (const float*)d_in[1];
    const float* pw  = (const float*)d_in[2];
    const float* pb  = (const float*)d_in[3];
    const float* w1  = (const float*)d_in[4];
    const float* b1  = (const float*)d_in[5];
    const float* w2  = (const float*)d_in[6];
    const float* b2  = (const float*)d_in[7];
    const float* w3  = (const float*)d_in[8];
    const float* b3  = (const float*)d_in[9];
    float* out = (float*)d_out;

    const int B = in_sizes[0] / NNODE;                    // 131072
    const int grid = (B + BLK2 - 1) / BLK2;               // 3277 blocks
    const size_t ldsBytes = 2 * BUF_B;                    // 51,840 B -> 3 blocks/CU

    hipFuncSetAttribute(reinterpret_cast<const void*>(gcnn_fused),
                        hipFuncAttributeMaxDynamicSharedMemorySize, (int)ldsBytes);

    gcnn_fused<<<grid, 256, ldsBytes, stream>>>(nf, adj, pw, pb, w1, b1, w2, b2, w3, b3, out, B);
}

// Round 9
// 36.018 us; speedup vs baseline: 1.4059x; 1.3585x over previous
//
#include <hip/hip_runtime.h>

#define NNODE  18
#define ADJ_B  1296                     // bytes per batch matrix
#define ADJ_F  324                      // floats per batch matrix
#define TILE   16                       // batches per 1-wave block (16 quads = full packing)
#define TILE_B (TILE * ADJ_B)           // 20,736 B static LDS -> 7 blocks/CU

__device__ __forceinline__ void gload_lds16(const void* g, void* l) {
    __builtin_amdgcn_global_load_lds((const __attribute__((address_space(1))) void*)g,
                                     (__attribute__((address_space(3))) void*)l, 16, 0, 0);
}

// quad_perm broadcast of lane P within each 4-lane group (bit15=1 -> quad mode)
#define QB(v, P) __int_as_float(__builtin_amdgcn_ds_swizzle(__float_as_int(v), 0x8000 + 0x55 * (P)))
#define GATHER18(dst, src)                                                      \
    dst[0]=QB(src[0],0);  dst[1]=QB(src[0],1);  dst[2]=QB(src[0],2);  dst[3]=QB(src[0],3);   \
    dst[4]=QB(src[1],0);  dst[5]=QB(src[1],1);  dst[6]=QB(src[1],2);  dst[7]=QB(src[1],3);   \
    dst[8]=QB(src[2],0);  dst[9]=QB(src[2],1);  dst[10]=QB(src[2],2); dst[11]=QB(src[2],3);  \
    dst[12]=QB(src[3],0); dst[13]=QB(src[3],1); dst[14]=QB(src[3],2); dst[15]=QB(src[3],3);  \
    dst[16]=QB(src[4],0); dst[17]=QB(src[4],1);

__global__ __launch_bounds__(64, 1) void gcnn_fused(
    const float* __restrict__ nf, const float* __restrict__ adj,
    const float* __restrict__ proj_w, const float* __restrict__ proj_b,
    const float* __restrict__ w1, const float* __restrict__ b1,
    const float* __restrict__ w2, const float* __restrict__ b2,
    const float* __restrict__ w3, const float* __restrict__ b3,
    float* __restrict__ out, int B)
{
    __shared__ __align__(16) char smem[TILE_B];    // single buffer, LINEAR (DMA dest)
    const int lane = threadIdx.x;                  // block = 1 wave: NO barriers anywhere
    const int p    = lane & 3;                     // quad lane: owns rows r ≡ p (mod 4)
    const int Q    = lane >> 2;                    // quad = batch within tile (0..15)
    const int b    = blockIdx.x * TILE + Q;
    const unsigned adjLim = (unsigned)B * ADJ_B - 16;   // tail clamp (B%16==0 -> never hit)

    // ---- Stage: 21 DMA ops, issued back-to-back, nothing waits until vmcnt(0) ----
    const unsigned gbase = (unsigned)blockIdx.x * TILE_B + lane * 16u;
    #pragma unroll
    for (int c = 0; c < 20; ++c)
        gload_lds16((const char*)adj + min(gbase + c * 1024u, adjLim), smem + c * 1024);
    if (lane < 16)                                 // tail 256 B of the tile
        gload_lds16((const char*)adj + min(gbase + 20480u, adjLim), smem + 20480);

    // ---- x loads: quad-uniform addresses; latency shares the DMA drain window ----
    const bool act = b < B;
    float x[NNODE];
    if (act) {
        const float2* __restrict__ xp = (const float2*)(nf + (size_t)b * NNODE);
        #pragma unroll
        for (int j = 0; j < 9; ++j) { float2 v = xp[j]; x[2*j] = v.x; x[2*j+1] = v.y; }
    }

    asm volatile("s_waitcnt vmcnt(0)" ::: "memory");    // tile + x resident (1-wave: no barrier)

    if (act) {
        // ---- LDS -> registers: lane p reads rows 4u+p of its quad's batch (~2-way conflict) ----
        float a[5][NNODE];
        const float* __restrict__ my = (const float*)smem + Q * ADJ_F;
        #pragma unroll
        for (int u = 0; u < 5; ++u) {
            int r  = 4 * u + p;
            int ro = r < NNODE ? r : NNODE - 1;    // lanes p>=2,u=4: clamped dummy (unused)
            const float2* __restrict__ rp = (const float2*)(my + ro * NNODE);
            #pragma unroll
            for (int j = 0; j < 9; ++j) { float2 v = rp[j]; a[u][2*j] = v.x; a[u][2*j+1] = v.y; }
        }
        const float pw = proj_w[0], pb = proj_b[0];

        // ---- Layer 1: h = relu(pw*(A x)/deg + pb), deg = row-sum (A·1 = deg, proj is 1x1) ----
        float inv[5], h[5];
        #pragma unroll
        for (int u = 0; u < 5; ++u) {
            float d = 0.f, s = 0.f;
            #pragma unroll
            for (int m = 0; m < NNODE; ++m) { d += a[u][m]; s += a[u][m] * x[m]; }
            inv[u] = 1.0f / d;
            h[u]   = fmaxf(0.f, pw * s * inv[u] + pb);
        }
        float hf[NNODE];
        GATHER18(hf, h)

        // ---- Layer 2 from register-resident A; NaN-scrub per reference ----
        float y[5];
        #pragma unroll
        for (int u = 0; u < 5; ++u) {
            float s = 0.f;
            #pragma unroll
            for (int m = 0; m < NNODE; ++m) s += a[u][m] * hf[m];
            float v = fmaxf(0.f, pw * s * inv[u] + pb);
            y[u] = (v != v) ? 0.f : v;
        }
        float yf[NNODE];
        GATHER18(yf, y)

        // ---- MLP head (quad-redundant; weights lane-uniform -> scalar/broadcast loads) ----
        float z1[10];
        #pragma unroll
        for (int k = 0; k < 10; ++k) {
            float s = b1[k];
            #pragma unroll
            for (int j = 0; j < NNODE; ++j) s += w1[k*NNODE + j] * yf[j];
            z1[k] = fmaxf(0.f, s);
        }
        float z2[8];
        #pragma unroll
        for (int k = 0; k < 8; ++k) {
            float s = b2[k];
            #pragma unroll
            for (int j = 0; j < 10; ++j) s += w2[k*10 + j] * z1[j];
            z2[k] = fmaxf(0.f, s);
        }
        float o0 = b3[0], o1 = b3[1];
        #pragma unroll
        for (int j = 0; j < 8; ++j) { o0 += w3[j] * z2[j]; o1 += w3[8 + j] * z2[j]; }

        if (p == 0)
            *(float2*)(out + (size_t)b * 2) = make_float2(o0, o1);   // 16x float2, contiguous
    }
}

extern "C" void kernel_launch(void* const* d_in, const int* in_sizes, int n_in,
                              void* d_out, int out_size, void* d_ws, size_t ws_size,
                              hipStream_t stream) {
    const float* nf  = (const float*)d_in[0];
    const float* adj = (const float*)d_in[1];
    const float* pw  = (const float*)d_in[2];
    const float* pb  = (const float*)d_in[3];
    const float* w1  = (const float*)d_in[4];
    const float* b1  = (const float*)d_in[5];
    const float* w2  = (const float*)d_in[6];
    const float* b2  = (const float*)d_in[7];
    const float* w3  = (const float*)d_in[8];
    const float* b3  = (const float*)d_in[9];
    float* out = (float*)d_out;

    const int B = in_sizes[0] / NNODE;                    // 131072
    const int grid = (B + TILE - 1) / TILE;               // 8192 one-wave blocks

    gcnn_fused<<<grid, 64, 0, stream>>>(nf, adj, pw, pb, w1, b1, w2, b2, w3, b3, out, B);
}